// Round 11
// baseline (133.371 us; speedup 1.0000x reference)
//
#include <hip/hip_runtime.h>
#include <hip/hip_bf16.h>
#include <stdint.h>

typedef unsigned short u16;
typedef __attribute__((ext_vector_type(8))) short bf16x8;   // 8 bf16 = 4 VGPR MFMA frag
typedef __attribute__((ext_vector_type(4))) float f32x4;    // MFMA accumulator frag

#define MFMA16(a,b,c) __builtin_amdgcn_mfma_f32_16x16x32_bf16((a),(b),(c),0,0,0)

__device__ __forceinline__ u16 f2bf(float f) {
    union { float f; uint32_t u; } v; v.f = f;
    return (u16)((v.u + 0x7FFFu + ((v.u >> 16) & 1u)) >> 16);   // RNE
}

// ---------------- x: f32 -> bf16 flat (4 elems/thread) ----------------
__global__ void k_convert(const float* __restrict__ in, u16* __restrict__ out) {
    int i = (blockIdx.x * 256 + threadIdx.x) * 4;
    f32x4 v = *(const f32x4*)(in + i);
    uint64_t p = (uint64_t)f2bf(v[0]) | ((uint64_t)f2bf(v[1]) << 16)
               | ((uint64_t)f2bf(v[2]) << 32) | ((uint64_t)f2bf(v[3]) << 48);
    *(uint64_t*)(out + i) = p;
}

// -------- W [R][NC] f32  ->  WT [NC][R] bf16 (wave-coalesced reads) --------
__global__ void k_transpose_convert(const float* __restrict__ W, u16* __restrict__ WT,
                                    int R, int NC) {
    int id = blockIdx.x * 256 + threadIdx.x;
    int n = id % NC, kc = id / NC;
    bf16x8 o;
#pragma unroll
    for (int i = 0; i < 8; ++i)
        o[i] = (short)f2bf(W[(size_t)(kc * 8 + i) * NC + n]);
    *(bf16x8*)(WT + (size_t)n * R + kc * 8) = o;
}

// -------- V [32][2048][64] bf16 -> Vt [32][64][2048] bf16 --------
__global__ void k_transpose_v(const u16* __restrict__ V, u16* __restrict__ Vt) {
    int id = blockIdx.x * 256 + threadIdx.x;
    int d = id & 63, tc = (id >> 6) & 255, bh = id >> 14;
    const u16* src = V + (size_t)bh * 131072 + d;
    u16* dst = Vt + (size_t)bh * 131072 + (size_t)d * 2048 + tc * 8;
    bf16x8 o;
#pragma unroll
    for (int i = 0; i < 8; ++i) o[i] = (short)src[(size_t)(tc * 8 + i) * 64];
    *(bf16x8*)dst = o;
}

// ============ QKV GEMM: tile 256x256, BK=32, 8 waves (2x4), wave tile 128x64 ============
// Rationale (r10 counters): the 128^2/64x64-wave structure is ds_read_b128
// ISSUE-bound (~12cy/instr: 96 reads/CU-kstep == 1142cy measured). 128x64 wave
// tile raises FLOP/ds_read 33% and halves staging-writes/FLOP (1.5x fewer LDS
// ops per FLOP). Skeleton = r10-verified 3-deep counted-vmcnt (tile-granular
// staging, no half-tile races): stage k+2 while computing k; end-of-iter
// s_waitcnt vmcnt(4) keeps tile k+2's loads in flight across the barrier.
// XOR chunk swizzle on global source + ds_read addr (both-sides, LDS linear).
// Scatters to qkv [3][B=2][H=16][T=2048][D=64] bf16, q scaled by 0.125.
__global__ __launch_bounds__(512, 2) void k_gemm_qkv(
    const u16* __restrict__ A, const u16* __restrict__ Bt,
    const float* __restrict__ bias, u16* __restrict__ outQKV,
    int M, int N, int K)
{
    __shared__ __align__(16) u16 As[3][256 * 32];   // 48 KB
    __shared__ __align__(16) u16 Bs[3][256 * 32];   // 48 KB
    const int tid = threadIdx.x;
    const int nbx = N >> 8;
    const int bm = blockIdx.x / nbx, bn = blockIdx.x % nbx;
    const int m0 = bm << 8, n0 = bn << 8;
    const int l = tid & 63, w = tid >> 6;          // 8 waves
    const int wr = w >> 2, wc = w & 3;             // 2 x 4 wave grid
    const int kl = l >> 4, lr = l & 15;

    const u16* Ag = A + (size_t)m0 * K;
    const u16* Bg = Bt + (size_t)n0 * K;

    // staging map: 1024 16B-chunks per 256x32 tile; wave w stages chunks
    // [(2w+s)*64 + l]; swizzled GLOBAL source, linear LDS dest (rule #21)
    int g_src[2], g_dst[2];
#pragma unroll
    for (int s = 0; s < 2; ++s) {
        int cb = (w * 2 + s) * 64;                 // wave-uniform base chunk
        int c = cb + l;
        int r = c >> 2, kc = c & 3;
        g_src[s] = r * K + ((kc ^ ((r >> 1) & 3)) << 3);
        g_dst[s] = cb << 3;                        // u16 elems, wave-uniform
    }

    // fragment read offsets with matching XOR swizzle
    int ra[8], rb[4];
#pragma unroll
    for (int m = 0; m < 8; ++m) {
        int row = wr * 128 + m * 16 + lr;
        ra[m] = row * 32 + (((kl ^ (row >> 1)) & 3) << 3);
    }
#pragma unroll
    for (int n = 0; n < 4; ++n) {
        int row = wc * 64 + n * 16 + lr;
        rb[n] = row * 32 + (((kl ^ (row >> 1)) & 3) << 3);
    }

    f32x4 acc[8][4] = {};

    auto STAGE = [&](int buf, int koff) {          // 4 gload_lds per thread
#pragma unroll
        for (int s = 0; s < 2; ++s) {
            __builtin_amdgcn_global_load_lds(Ag + g_src[s] + koff,
                                             &As[buf][g_dst[s]], 16, 0, 0);
            __builtin_amdgcn_global_load_lds(Bg + g_src[s] + koff,
                                             &Bs[buf][g_dst[s]], 16, 0, 0);
        }
    };

    // prologue: stage tiles 0,1; wait for tile 0 only (tile 1 stays in flight)
    STAGE(0, 0);
    STAGE(1, 32);
    asm volatile("s_waitcnt vmcnt(4)" ::: "memory");
    __builtin_amdgcn_s_barrier();
    __builtin_amdgcn_sched_barrier(0);

    const int nK = K >> 5;
    int rd = 0;
    for (int ks = 0; ks < nK; ++ks) {
        const bool st = (ks + 2 < nK);
        if (st) {
            int sb = rd + 2; if (sb >= 3) sb -= 3;
            STAGE(sb, (ks + 2) << 5);
        }
        bf16x8 af[8], bfr[4];
#pragma unroll
        for (int m = 0; m < 8; ++m) af[m] = *(const bf16x8*)&As[rd][ra[m]];
#pragma unroll
        for (int n = 0; n < 4; ++n) bfr[n] = *(const bf16x8*)&Bs[rd][rb[n]];
#pragma unroll
        for (int m = 0; m < 8; ++m)
#pragma unroll
            for (int n = 0; n < 4; ++n)
                acc[m][n] = MFMA16(af[m], bfr[n], acc[m][n]);
        if (ks + 1 < nK) {
            if (st) asm volatile("s_waitcnt vmcnt(4)" ::: "memory");
            else    asm volatile("s_waitcnt vmcnt(0)" ::: "memory");
            __builtin_amdgcn_s_barrier();
            __builtin_amdgcn_sched_barrier(0);
        }
        rd = (rd == 2) ? 0 : rd + 1;
    }

    // epilogue: scatter to qkv layout, fold 0.125 into q
#pragma unroll
    for (int n = 0; n < 4; ++n) {
        int gn = n0 + wc * 64 + n * 16 + lr;
        float bv = bias[gn];
        int s = gn >> 10, hd = gn & 1023;
        int hh = hd >> 6, dd = hd & 63;
        float mult = (s == 0) ? 0.125f : 1.0f;
        size_t base = (size_t)s * 4194304 + (size_t)hh * 131072 + dd;
#pragma unroll
        for (int m = 0; m < 8; ++m)
#pragma unroll
            for (int j = 0; j < 4; ++j) {
                int gm = m0 + wr * 128 + m * 16 + kl * 4 + j;
                int bb = gm >> 11, tt = gm & 2047;
                float val = (acc[m][n][j] + bv) * mult;
                outQKV[base + (size_t)bb * 2097152 + (size_t)tt * 64] = f2bf(val);
            }
    }
}

// ---------------- proj GEMM (unchanged r10 structure, NREP=2, fp32 out) ----------------
template<int NREP, int MODE>
__device__ __forceinline__ void gemm_body(
    const u16* __restrict__ A, const u16* __restrict__ Bt,
    const float* __restrict__ bias,
    u16* __restrict__ outQKV, float* __restrict__ outF,
    int M, int N, int K)
{
    constexpr int BN = 32 * NREP;
    constexpr int WN = 16 * NREP;
    constexpr int BSLOTS = NREP / 2;
    __shared__ __align__(16) u16 As[3][128 * 32];
    __shared__ __align__(16) u16 Bs[3][BN * 32];
    const int tid = threadIdx.x;
    const int nbx = N / BN;
    const int bm = blockIdx.x / nbx, bn = blockIdx.x % nbx;
    const int m0 = bm << 7, n0 = bn * BN;
    const int l = tid & 63, w = tid >> 6;
    const int wr = w >> 1, wc = w & 1;
    const int kl = l >> 4, lr = l & 15;

    const u16* Ag = A + (size_t)m0 * K;
    const u16* Bg = Bt + (size_t)n0 * K;

    int a_src[2], a_dst[2];
#pragma unroll
    for (int s = 0; s < 2; ++s) {
        int cb = w * 128 + s * 64;
        int c = cb + l;
        int r = c >> 2, kc = c & 3;
        a_src[s] = r * K + ((kc ^ ((r >> 1) & 3)) << 3);
        a_dst[s] = cb << 3;
    }
    int b_src[BSLOTS], b_dst[BSLOTS];
#pragma unroll
    for (int s = 0; s < BSLOTS; ++s) {
        int cb = (w * BSLOTS + s) * 64;
        int c = cb + l;
        int r = c >> 2, kc = c & 3;
        b_src[s] = r * K + ((kc ^ ((r >> 1) & 3)) << 3);
        b_dst[s] = cb << 3;
    }

    int ra[4], rb[NREP];
#pragma unroll
    for (int m = 0; m < 4; ++m) {
        int row = wr * 64 + m * 16 + lr;
        ra[m] = row * 32 + (((kl ^ (row >> 1)) & 3) << 3);
    }
#pragma unroll
    for (int n = 0; n < NREP; ++n) {
        int row = wc * WN + n * 16 + lr;
        rb[n] = row * 32 + (((kl ^ (row >> 1)) & 3) << 3);
    }

    f32x4 acc[4][NREP] = {};

    auto STAGE = [&](int buf, int koff) {
#pragma unroll
        for (int s = 0; s < 2; ++s)
            __builtin_amdgcn_global_load_lds(Ag + a_src[s] + koff,
                                             &As[buf][a_dst[s]], 16, 0, 0);
#pragma unroll
        for (int s = 0; s < BSLOTS; ++s)
            __builtin_amdgcn_global_load_lds(Bg + b_src[s] + koff,
                                             &Bs[buf][b_dst[s]], 16, 0, 0);
    };

    STAGE(0, 0);
    STAGE(1, 32);
    asm volatile("s_waitcnt vmcnt(3)" ::: "memory");
    __builtin_amdgcn_s_barrier();
    __builtin_amdgcn_sched_barrier(0);

    const int nK = K >> 5;
    int rd = 0;
    for (int ks = 0; ks < nK; ++ks) {
        const bool st = (ks + 2 < nK);
        if (st) {
            int sb = rd + 2; if (sb >= 3) sb -= 3;
            STAGE(sb, (ks + 2) << 5);
        }
        bf16x8 af[4], bfr[NREP];
#pragma unroll
        for (int m = 0; m < 4; ++m) af[m] = *(const bf16x8*)&As[rd][ra[m]];
#pragma unroll
        for (int n = 0; n < NREP; ++n) bfr[n] = *(const bf16x8*)&Bs[rd][rb[n]];
#pragma unroll
        for (int m = 0; m < 4; ++m)
#pragma unroll
            for (int n = 0; n < NREP; ++n)
                acc[m][n] = MFMA16(af[m], bfr[n], acc[m][n]);
        if (ks + 1 < nK) {
            if (st) asm volatile("s_waitcnt vmcnt(3)" ::: "memory");
            else    asm volatile("s_waitcnt vmcnt(0)" ::: "memory");
            __builtin_amdgcn_s_barrier();
            __builtin_amdgcn_sched_barrier(0);
        }
        rd = (rd == 2) ? 0 : rd + 1;
    }

#pragma unroll
    for (int n = 0; n < NREP; ++n) {
        int gn = n0 + wc * WN + n * 16 + lr;
        float bv = bias[gn];
#pragma unroll
        for (int m = 0; m < 4; ++m)
#pragma unroll
            for (int j = 0; j < 4; ++j) {
                int gm = m0 + wr * 64 + m * 16 + kl * 4 + j;
                outF[(size_t)gm * N + gn] = acc[m][n][j] + bv;
            }
    }
}

__global__ __launch_bounds__(256, 3) void k_gemm_proj(
    const u16* __restrict__ A, const u16* __restrict__ Bt,
    const float* __restrict__ bias, float* __restrict__ outF,
    int M, int N, int K)
{
    gemm_body<2, 1>(A, Bt, bias, nullptr, outF, M, N, K);
}

// ---------------- causal flash attention (unchanged) ----------------
__global__ __launch_bounds__(256, 4) void k_attn(
    const u16* __restrict__ Qg, const u16* __restrict__ Kg,
    const u16* __restrict__ Vtg, u16* __restrict__ Yg)
{
    const int bid = blockIdx.x;
    const int bh = bid & 31;
    const int qt = 31 - (bid >> 5);
    const int b = bh >> 4, h = bh & 15;
    const int q0 = qt << 6;
    const int tid = threadIdx.x, l = tid & 63, w = tid >> 6;
    const int kl = l >> 4, lr = l & 15;

    __shared__ __align__(16) u16 Qs[64 * 64];
    __shared__ __align__(16) u16 Ks[64 * 64];
    __shared__ __align__(16) u16 Vs[64 * 64];
    __shared__ __align__(16) u16 Ps[4][16 * 72];

    const u16* Qb = Qg + (size_t)bh * 131072;
    const u16* Kb = Kg + (size_t)bh * 131072;
    const u16* Vb = Vtg + (size_t)bh * 131072;

    const int rr = tid >> 3, ch = tid & 7;
    {
        bf16x8 a = *(const bf16x8*)(Qb + (size_t)(q0 + rr) * 64 + ch * 8);
        bf16x8 c = *(const bf16x8*)(Qb + (size_t)(q0 + rr + 32) * 64 + ch * 8);
        *(bf16x8*)&Qs[rr * 64 + ((ch ^ (rr & 7)) << 3)] = a;
        *(bf16x8*)&Qs[(rr + 32) * 64 + ((ch ^ (rr & 7)) << 3)] = c;
    }
    __syncthreads();
    bf16x8 qa[2];
#pragma unroll
    for (int kk = 0; kk < 2; ++kk) {
        int row = w * 16 + lr;
        qa[kk] = *(const bf16x8*)&Qs[row * 64 + (((kk * 4 + kl) ^ (row & 7)) << 3)];
    }

    f32x4 oacc[4] = {};
    float lsum[4] = {0.f, 0.f, 0.f, 0.f};

    bf16x8 kv0 = *(const bf16x8*)(Kb + (size_t)rr * 64 + ch * 8);
    bf16x8 kv1 = *(const bf16x8*)(Kb + (size_t)(rr + 32) * 64 + ch * 8);
    bf16x8 vv0 = *(const bf16x8*)(Vb + (size_t)rr * 2048 + ch * 8);
    bf16x8 vv1 = *(const bf16x8*)(Vb + (size_t)(rr + 32) * 2048 + ch * 8);

    for (int kt = 0; kt <= qt; ++kt) {
        const int k0 = kt << 6;
        __syncthreads();
        *(bf16x8*)&Ks[rr * 64 + ((ch ^ (rr & 7)) << 3)] = kv0;
        *(bf16x8*)&Ks[(rr + 32) * 64 + ((ch ^ (rr & 7)) << 3)] = kv1;
        *(bf16x8*)&Vs[rr * 64 + ((ch ^ (rr & 7)) << 3)] = vv0;
        *(bf16x8*)&Vs[(rr + 32) * 64 + ((ch ^ (rr & 7)) << 3)] = vv1;
        __syncthreads();
        if (kt < qt) {
            const int k0n = k0 + 64;
            kv0 = *(const bf16x8*)(Kb + (size_t)(k0n + rr) * 64 + ch * 8);
            kv1 = *(const bf16x8*)(Kb + (size_t)(k0n + rr + 32) * 64 + ch * 8);
            vv0 = *(const bf16x8*)(Vb + (size_t)rr * 2048 + k0n + ch * 8);
            vv1 = *(const bf16x8*)(Vb + (size_t)(rr + 32) * 2048 + k0n + ch * 8);
        }

        f32x4 s[4];
#pragma unroll
        for (int nb = 0; nb < 4; ++nb) {
            f32x4 a = {};
            int key = nb * 16 + lr;
#pragma unroll
            for (int kk = 0; kk < 2; ++kk) {
                bf16x8 kb = *(const bf16x8*)&Ks[key * 64 + (((kk * 4 + kl) ^ (key & 7)) << 3)];
                a = MFMA16(qa[kk], kb, a);
            }
            s[nb] = a;
        }
        if (kt == qt) {
#pragma unroll
            for (int nb = 0; nb < 4; ++nb) {
                int key = k0 + nb * 16 + lr;
#pragma unroll
                for (int j = 0; j < 4; ++j) {
                    int q = q0 + w * 16 + kl * 4 + j;
                    if (key > q) s[nb][j] = -__builtin_inff();
                }
            }
        }
#pragma unroll
        for (int j = 0; j < 4; ++j) {
            float acc4 = 0.f;
#pragma unroll
            for (int nb = 0; nb < 4; ++nb) {
                float p = __expf(s[nb][j]);
                s[nb][j] = p;
                acc4 += p;
            }
            lsum[j] += acc4;
        }
#pragma unroll
        for (int nb = 0; nb < 4; ++nb)
#pragma unroll
            for (int j = 0; j < 4; ++j)
                Ps[w][(kl * 4 + j) * 72 + nb * 16 + lr] = f2bf(s[nb][j]);
        bf16x8 pa[2];
#pragma unroll
        for (int kk = 0; kk < 2; ++kk)
            pa[kk] = *(const bf16x8*)&Ps[w][lr * 72 + kk * 32 + kl * 8];
#pragma unroll
        for (int db = 0; db < 4; ++db) {
            int d = db * 16 + lr;
#pragma unroll
            for (int kk = 0; kk < 2; ++kk) {
                bf16x8 vb = *(const bf16x8*)&Vs[d * 64 + (((kk * 4 + kl) ^ (d & 7)) << 3)];
                oacc[db] = MFMA16(pa[kk], vb, oacc[db]);
            }
        }
    }
#pragma unroll
    for (int j = 0; j < 4; ++j) {
#pragma unroll
        for (int off = 1; off < 16; off <<= 1) lsum[j] += __shfl_xor(lsum[j], off);
        lsum[j] = 1.f / lsum[j];
    }
#pragma unroll
    for (int db = 0; db < 4; ++db)
#pragma unroll
        for (int j = 0; j < 4; ++j) {
            int q = q0 + w * 16 + kl * 4 + j;
            int col = h * 64 + db * 16 + lr;
            Yg[(size_t)(b * 2048 + q) * 1024 + col] = f2bf(oacc[db][j] * lsum[j]);
        }
}

extern "C" void kernel_launch(void* const* d_in, const int* in_sizes, int n_in,
                              void* d_out, int out_size, void* d_ws, size_t ws_size,
                              hipStream_t stream) {
    const float* x     = (const float*)d_in[0];
    const float* Wqkv  = (const float*)d_in[1];
    const float* bqkv  = (const float*)d_in[2];
    const float* Wproj = (const float*)d_in[3];
    const float* bproj = (const float*)d_in[4];
    float* out = (float*)d_out;

    char* ws = (char*)d_ws;
    u16* xb     = (u16*)(ws);                 // 8,388,608 B  (reused as Vt later)
    u16* WqkvT  = (u16*)(ws + 8388608);       // 6,291,456 B
    u16* WprojT = (u16*)(ws + 14680064);      // 2,097,152 B
    u16* qkv    = (u16*)(ws + 16777216);      // 25,165,824 B : [3][2][16][2048][64]
    u16* Vt   = xb;                            // xb free after GEMM1
    u16* Yatt = qkv + 2 * 4194304;             // v-slot free after transpose_v

    k_convert<<<4096, 256, 0, stream>>>(x, xb);                              // x -> bf16
    k_transpose_convert<<<1536, 256, 0, stream>>>(Wqkv, WqkvT, 1024, 3072);  // Wqkv^T bf16
    k_transpose_convert<<<512, 256, 0, stream>>>(Wproj, WprojT, 1024, 1024); // Wproj^T bf16
    k_gemm_qkv<<<192, 512, 0, stream>>>(xb, WqkvT, bqkv, qkv,
                                        4096, 3072, 1024);                   // qkv (256^2 tiles)
    k_transpose_v<<<2048, 256, 0, stream>>>(qkv + 2 * 4194304, Vt);          // V -> [d][t]
    k_attn<<<1024, 256, 0, stream>>>(qkv, qkv + 4194304, Vt, Yatt);          // attention
    k_gemm_proj<<<512, 256, 0, stream>>>(Yatt, WprojT, bproj, out,
                                         4096, 1024, 1024);                  // projection
}

// Round 12
// 129.286 us; speedup vs baseline: 1.0316x; 1.0316x over previous
//
#include <hip/hip_runtime.h>
#include <hip/hip_bf16.h>
#include <stdint.h>

typedef unsigned short u16;
typedef __attribute__((ext_vector_type(8))) short bf16x8;   // 8 bf16 = 4 VGPR MFMA frag
typedef __attribute__((ext_vector_type(4))) float f32x4;    // MFMA accumulator frag

#define MFMA16(a,b,c) __builtin_amdgcn_mfma_f32_16x16x32_bf16((a),(b),(c),0,0,0)

__device__ __forceinline__ u16 f2bf(float f) {
    union { float f; uint32_t u; } v; v.f = f;
    return (u16)((v.u + 0x7FFFu + ((v.u >> 16) & 1u)) >> 16);   // RNE
}

// ---------------- x: f32 -> bf16 flat (4 elems/thread) ----------------
__global__ void k_convert(const float* __restrict__ in, u16* __restrict__ out) {
    int i = (blockIdx.x * 256 + threadIdx.x) * 4;
    f32x4 v = *(const f32x4*)(in + i);
    uint64_t p = (uint64_t)f2bf(v[0]) | ((uint64_t)f2bf(v[1]) << 16)
               | ((uint64_t)f2bf(v[2]) << 32) | ((uint64_t)f2bf(v[3]) << 48);
    *(uint64_t*)(out + i) = p;
}

// -------- W [R][NC] f32  ->  WT [NC][R] bf16 (wave-coalesced reads) --------
__global__ void k_transpose_convert(const float* __restrict__ W, u16* __restrict__ WT,
                                    int R, int NC) {
    int id = blockIdx.x * 256 + threadIdx.x;
    int n = id % NC, kc = id / NC;
    bf16x8 o;
#pragma unroll
    for (int i = 0; i < 8; ++i)
        o[i] = (short)f2bf(W[(size_t)(kc * 8 + i) * NC + n]);
    *(bf16x8*)(WT + (size_t)n * R + kc * 8) = o;
}

// -------- V [32][2048][64] bf16 -> Vt [32][64][2048] bf16 --------
__global__ void k_transpose_v(const u16* __restrict__ V, u16* __restrict__ Vt) {
    int id = blockIdx.x * 256 + threadIdx.x;
    int d = id & 63, tc = (id >> 6) & 255, bh = id >> 14;
    const u16* src = V + (size_t)bh * 131072 + d;
    u16* dst = Vt + (size_t)bh * 131072 + (size_t)d * 2048 + tc * 8;
    bf16x8 o;
#pragma unroll
    for (int i = 0; i < 8; ++i) o[i] = (short)src[(size_t)(tc * 8 + i) * 64];
    *(bf16x8*)dst = o;
}

// ============ QKV GEMM: 8-phase 256^2 template (T3+T4+T5), BK=64 ============
// r11 lesson: coarse phase-split at 1 block/CU regressed (m196 mechanism).
// This is the fine-interleaved schedule: per K-tile 4 phases, each
// {ds_read subtile || stage 1 K-half -> s_barrier -> setprio(1) 16xMFMA
//  setprio(0) [-> vmcnt(4)] -> s_barrier}. vmcnt counted (4 = 2 half-tiles
// in flight), never drained mid-loop. Per-wave vmcnt + barrier publishes
// cross-wave: newest-4 at each vmcnt are exactly the 2 halves staged since,
// so all older stages (the halves the next phase reads) have landed.
// LDS [2dbuf][2 K-half] for A and B = 128KB, 1 block/CU, 8 waves (2Mx4N),
// wave tile 128x64, acc 8x4. Swizzle both-sides: global src pre-swizzled
// j^(r&3), ds_read matched; LDS dest linear (rule #21).
__global__ __launch_bounds__(512, 1) void k_gemm_qkv(
    const u16* __restrict__ A, const u16* __restrict__ Bt,
    const float* __restrict__ bias, u16* __restrict__ outQKV,
    int M, int N, int K)
{
    __shared__ __align__(16) u16 As[2][2][256 * 32];   // 64 KB
    __shared__ __align__(16) u16 Bs[2][2][256 * 32];   // 64 KB
    const int tid = threadIdx.x;
    const int nbx = N >> 8;
    const int bm = blockIdx.x / nbx, bn = blockIdx.x % nbx;
    const int m0 = bm << 8, n0 = bn << 8;
    const int l = tid & 63, w = tid >> 6;              // 8 waves
    const int wr = w >> 2, wc = w & 3;                 // 2 x 4 wave grid
    const int kl = l >> 4, lr = l & 15;

    const u16* Ag = A + (size_t)m0 * K;
    const u16* Bg = Bt + (size_t)n0 * K;

    // staging: one K-half (256 rows x 32 cols = 1024 16B-chunks) per call;
    // wave w covers chunks cb+l, cb = w*128 + s*64; global src pre-swizzled
    int goff[2], dstc[2];
#pragma unroll
    for (int s = 0; s < 2; ++s) {
        int cb = w * 128 + s * 64;
        int c = cb + l;
        int r = c >> 2, j = c & 3;
        goff[s] = r * K + ((j ^ (r & 3)) << 3);
        dstc[s] = cb << 3;                             // u16 elems, wave-uniform
    }

    // frag read offsets (elems within one K-half region), swizzle-matched
    int ra[8], rb[4];
#pragma unroll
    for (int m = 0; m < 8; ++m) {
        int row = wr * 128 + m * 16 + lr;
        ra[m] = (row * 4 + (kl ^ (row & 3))) * 8;
    }
#pragma unroll
    for (int n = 0; n < 4; ++n) {
        int row = wc * 64 + n * 16 + lr;
        rb[n] = (row * 4 + (kl ^ (row & 3))) * 8;
    }

    f32x4 acc[8][4] = {};

    auto SA = [&](int buf, int kh, int t) {
        int kb = t * 64 + kh * 32;
#pragma unroll
        for (int s = 0; s < 2; ++s)
            __builtin_amdgcn_global_load_lds(Ag + goff[s] + kb,
                                             &As[buf][kh][dstc[s]], 16, 0, 0);
    };
    auto SB = [&](int buf, int kh, int t) {
        int kb = t * 64 + kh * 32;
#pragma unroll
        for (int s = 0; s < 2; ++s)
            __builtin_amdgcn_global_load_lds(Bg + goff[s] + kb,
                                             &Bs[buf][kh][dstc[s]], 16, 0, 0);
    };

    // prologue: issue all 4 halves of tile 0; wait K-half0 pair only
    SA(0, 0, 0); SB(0, 0, 0); SA(0, 1, 0); SB(0, 1, 0);
    asm volatile("s_waitcnt vmcnt(4)" ::: "memory");
    asm volatile("s_barrier" ::: "memory");

    const int nT = K >> 6;                             // 16 K-tiles
    for (int t = 0; t < nT; ++t) {
        const int cur = t & 1, nxt = cur ^ 1;
        const bool pre = (t + 1 < nT);
        bf16x8 af[8], bfr[4];
        // ---- phase 1: ds ks0 (12 reads) | stage A(nxt,K0) | MFMA n0-1 ks0 ----
#pragma unroll
        for (int m = 0; m < 8; ++m) af[m] = *(const bf16x8*)&As[cur][0][ra[m]];
#pragma unroll
        for (int n = 0; n < 4; ++n) bfr[n] = *(const bf16x8*)&Bs[cur][0][rb[n]];
        if (pre) SA(nxt, 0, t + 1);
        asm volatile("s_barrier" ::: "memory");
        __builtin_amdgcn_s_setprio(1);
#pragma unroll
        for (int m = 0; m < 8; ++m)
#pragma unroll
            for (int n = 0; n < 2; ++n)
                acc[m][n] = MFMA16(af[m], bfr[n], acc[m][n]);
        __builtin_amdgcn_s_setprio(0);
        asm volatile("s_barrier" ::: "memory");
        // ---- phase 2: stage B(nxt,K0) | MFMA n2-3 ks0 | vmcnt ----
        if (pre) SB(nxt, 0, t + 1);
        asm volatile("s_barrier" ::: "memory");
        __builtin_amdgcn_s_setprio(1);
#pragma unroll
        for (int m = 0; m < 8; ++m)
#pragma unroll
            for (int n = 2; n < 4; ++n)
                acc[m][n] = MFMA16(af[m], bfr[n], acc[m][n]);
        __builtin_amdgcn_s_setprio(0);
        if (pre) asm volatile("s_waitcnt vmcnt(4)" ::: "memory");
        else     asm volatile("s_waitcnt vmcnt(0)" ::: "memory");
        asm volatile("s_barrier" ::: "memory");
        // ---- phase 3: ds ks1 (12 reads) | stage A(nxt,K1) | MFMA n0-1 ks1 ----
#pragma unroll
        for (int m = 0; m < 8; ++m) af[m] = *(const bf16x8*)&As[cur][1][ra[m]];
#pragma unroll
        for (int n = 0; n < 4; ++n) bfr[n] = *(const bf16x8*)&Bs[cur][1][rb[n]];
        if (pre) SA(nxt, 1, t + 1);
        asm volatile("s_barrier" ::: "memory");
        __builtin_amdgcn_s_setprio(1);
#pragma unroll
        for (int m = 0; m < 8; ++m)
#pragma unroll
            for (int n = 0; n < 2; ++n)
                acc[m][n] = MFMA16(af[m], bfr[n], acc[m][n]);
        __builtin_amdgcn_s_setprio(0);
        asm volatile("s_barrier" ::: "memory");
        // ---- phase 4: stage B(nxt,K1) | MFMA n2-3 ks1 | vmcnt ----
        if (pre) SB(nxt, 1, t + 1);
        asm volatile("s_barrier" ::: "memory");
        __builtin_amdgcn_s_setprio(1);
#pragma unroll
        for (int m = 0; m < 8; ++m)
#pragma unroll
            for (int n = 2; n < 4; ++n)
                acc[m][n] = MFMA16(af[m], bfr[n], acc[m][n]);
        __builtin_amdgcn_s_setprio(0);
        if (pre) asm volatile("s_waitcnt vmcnt(4)" ::: "memory");
        asm volatile("s_barrier" ::: "memory");
    }

    // epilogue: scatter to qkv [3][2][16][2048][64], fold 0.125 into q
#pragma unroll
    for (int n = 0; n < 4; ++n) {
        int gn = n0 + wc * 64 + n * 16 + lr;
        float bv = bias[gn];
        int s = gn >> 10, hd = gn & 1023;
        int hh = hd >> 6, dd = hd & 63;
        float mult = (s == 0) ? 0.125f : 1.0f;
        size_t base = (size_t)s * 4194304 + (size_t)hh * 131072 + dd;
#pragma unroll
        for (int m = 0; m < 8; ++m)
#pragma unroll
            for (int j = 0; j < 4; ++j) {
                int gm = m0 + wr * 128 + m * 16 + kl * 4 + j;
                int bb = gm >> 11, tt = gm & 2047;
                float val = (acc[m][n][j] + bv) * mult;
                outQKV[base + (size_t)bb * 2097152 + (size_t)tt * 64] = f2bf(val);
            }
    }
}

// ---------------- proj GEMM (r10-verified counted-vmcnt 128^2, NREP=2) ----------------
template<int NREP, int MODE>
__device__ __forceinline__ void gemm_body(
    const u16* __restrict__ A, const u16* __restrict__ Bt,
    const float* __restrict__ bias,
    u16* __restrict__ outQKV, float* __restrict__ outF,
    int M, int N, int K)
{
    constexpr int BN = 32 * NREP;
    constexpr int WN = 16 * NREP;
    constexpr int BSLOTS = NREP / 2;
    __shared__ __align__(16) u16 As[3][128 * 32];
    __shared__ __align__(16) u16 Bs[3][BN * 32];
    const int tid = threadIdx.x;
    const int nbx = N / BN;
    const int bm = blockIdx.x / nbx, bn = blockIdx.x % nbx;
    const int m0 = bm << 7, n0 = bn * BN;
    const int l = tid & 63, w = tid >> 6;
    const int wr = w >> 1, wc = w & 1;
    const int kl = l >> 4, lr = l & 15;

    const u16* Ag = A + (size_t)m0 * K;
    const u16* Bg = Bt + (size_t)n0 * K;

    int a_src[2], a_dst[2];
#pragma unroll
    for (int s = 0; s < 2; ++s) {
        int cb = w * 128 + s * 64;
        int c = cb + l;
        int r = c >> 2, kc = c & 3;
        a_src[s] = r * K + ((kc ^ ((r >> 1) & 3)) << 3);
        a_dst[s] = cb << 3;
    }
    int b_src[BSLOTS], b_dst[BSLOTS];
#pragma unroll
    for (int s = 0; s < BSLOTS; ++s) {
        int cb = (w * BSLOTS + s) * 64;
        int c = cb + l;
        int r = c >> 2, kc = c & 3;
        b_src[s] = r * K + ((kc ^ ((r >> 1) & 3)) << 3);
        b_dst[s] = cb << 3;
    }

    int ra[4], rb[NREP];
#pragma unroll
    for (int m = 0; m < 4; ++m) {
        int row = wr * 64 + m * 16 + lr;
        ra[m] = row * 32 + (((kl ^ (row >> 1)) & 3) << 3);
    }
#pragma unroll
    for (int n = 0; n < NREP; ++n) {
        int row = wc * WN + n * 16 + lr;
        rb[n] = row * 32 + (((kl ^ (row >> 1)) & 3) << 3);
    }

    f32x4 acc[4][NREP] = {};

    auto STAGE = [&](int buf, int koff) {
#pragma unroll
        for (int s = 0; s < 2; ++s)
            __builtin_amdgcn_global_load_lds(Ag + a_src[s] + koff,
                                             &As[buf][a_dst[s]], 16, 0, 0);
#pragma unroll
        for (int s = 0; s < BSLOTS; ++s)
            __builtin_amdgcn_global_load_lds(Bg + b_src[s] + koff,
                                             &Bs[buf][b_dst[s]], 16, 0, 0);
    };

    STAGE(0, 0);
    STAGE(1, 32);
    asm volatile("s_waitcnt vmcnt(3)" ::: "memory");
    __builtin_amdgcn_s_barrier();
    __builtin_amdgcn_sched_barrier(0);

    const int nK = K >> 5;
    int rd = 0;
    for (int ks = 0; ks < nK; ++ks) {
        const bool st = (ks + 2 < nK);
        if (st) {
            int sb = rd + 2; if (sb >= 3) sb -= 3;
            STAGE(sb, (ks + 2) << 5);
        }
        bf16x8 af[4], bfr[NREP];
#pragma unroll
        for (int m = 0; m < 4; ++m) af[m] = *(const bf16x8*)&As[rd][ra[m]];
#pragma unroll
        for (int n = 0; n < NREP; ++n) bfr[n] = *(const bf16x8*)&Bs[rd][rb[n]];
#pragma unroll
        for (int m = 0; m < 4; ++m)
#pragma unroll
            for (int n = 0; n < NREP; ++n)
                acc[m][n] = MFMA16(af[m], bfr[n], acc[m][n]);
        if (ks + 1 < nK) {
            if (st) asm volatile("s_waitcnt vmcnt(3)" ::: "memory");
            else    asm volatile("s_waitcnt vmcnt(0)" ::: "memory");
            __builtin_amdgcn_s_barrier();
            __builtin_amdgcn_sched_barrier(0);
        }
        rd = (rd == 2) ? 0 : rd + 1;
    }

#pragma unroll
    for (int n = 0; n < NREP; ++n) {
        int gn = n0 + wc * WN + n * 16 + lr;
        float bv = bias[gn];
#pragma unroll
        for (int m = 0; m < 4; ++m)
#pragma unroll
            for (int j = 0; j < 4; ++j) {
                int gm = m0 + wr * 64 + m * 16 + kl * 4 + j;
                outF[(size_t)gm * N + gn] = acc[m][n][j] + bv;
            }
    }
}

__global__ __launch_bounds__(256, 3) void k_gemm_proj(
    const u16* __restrict__ A, const u16* __restrict__ Bt,
    const float* __restrict__ bias, float* __restrict__ outF,
    int M, int N, int K)
{
    gemm_body<2, 1>(A, Bt, bias, nullptr, outF, M, N, K);
}

// ---------------- causal flash attention (unchanged) ----------------
__global__ __launch_bounds__(256, 4) void k_attn(
    const u16* __restrict__ Qg, const u16* __restrict__ Kg,
    const u16* __restrict__ Vtg, u16* __restrict__ Yg)
{
    const int bid = blockIdx.x;
    const int bh = bid & 31;
    const int qt = 31 - (bid >> 5);
    const int b = bh >> 4, h = bh & 15;
    const int q0 = qt << 6;
    const int tid = threadIdx.x, l = tid & 63, w = tid >> 6;
    const int kl = l >> 4, lr = l & 15;

    __shared__ __align__(16) u16 Qs[64 * 64];
    __shared__ __align__(16) u16 Ks[64 * 64];
    __shared__ __align__(16) u16 Vs[64 * 64];
    __shared__ __align__(16) u16 Ps[4][16 * 72];

    const u16* Qb = Qg + (size_t)bh * 131072;
    const u16* Kb = Kg + (size_t)bh * 131072;
    const u16* Vb = Vtg + (size_t)bh * 131072;

    const int rr = tid >> 3, ch = tid & 7;
    {
        bf16x8 a = *(const bf16x8*)(Qb + (size_t)(q0 + rr) * 64 + ch * 8);
        bf16x8 c = *(const bf16x8*)(Qb + (size_t)(q0 + rr + 32) * 64 + ch * 8);
        *(bf16x8*)&Qs[rr * 64 + ((ch ^ (rr & 7)) << 3)] = a;
        *(bf16x8*)&Qs[(rr + 32) * 64 + ((ch ^ (rr & 7)) << 3)] = c;
    }
    __syncthreads();
    bf16x8 qa[2];
#pragma unroll
    for (int kk = 0; kk < 2; ++kk) {
        int row = w * 16 + lr;
        qa[kk] = *(const bf16x8*)&Qs[row * 64 + (((kk * 4 + kl) ^ (row & 7)) << 3)];
    }

    f32x4 oacc[4] = {};
    float lsum[4] = {0.f, 0.f, 0.f, 0.f};

    bf16x8 kv0 = *(const bf16x8*)(Kb + (size_t)rr * 64 + ch * 8);
    bf16x8 kv1 = *(const bf16x8*)(Kb + (size_t)(rr + 32) * 64 + ch * 8);
    bf16x8 vv0 = *(const bf16x8*)(Vb + (size_t)rr * 2048 + ch * 8);
    bf16x8 vv1 = *(const bf16x8*)(Vb + (size_t)(rr + 32) * 2048 + ch * 8);

    for (int kt = 0; kt <= qt; ++kt) {
        const int k0 = kt << 6;
        __syncthreads();
        *(bf16x8*)&Ks[rr * 64 + ((ch ^ (rr & 7)) << 3)] = kv0;
        *(bf16x8*)&Ks[(rr + 32) * 64 + ((ch ^ (rr & 7)) << 3)] = kv1;
        *(bf16x8*)&Vs[rr * 64 + ((ch ^ (rr & 7)) << 3)] = vv0;
        *(bf16x8*)&Vs[(rr + 32) * 64 + ((ch ^ (rr & 7)) << 3)] = vv1;
        __syncthreads();
        if (kt < qt) {
            const int k0n = k0 + 64;
            kv0 = *(const bf16x8*)(Kb + (size_t)(k0n + rr) * 64 + ch * 8);
            kv1 = *(const bf16x8*)(Kb + (size_t)(k0n + rr + 32) * 64 + ch * 8);
            vv0 = *(const bf16x8*)(Vb + (size_t)rr * 2048 + k0n + ch * 8);
            vv1 = *(const bf16x8*)(Vb + (size_t)(rr + 32) * 2048 + k0n + ch * 8);
        }

        f32x4 s[4];
#pragma unroll
        for (int nb = 0; nb < 4; ++nb) {
            f32x4 a = {};
            int key = nb * 16 + lr;
#pragma unroll
            for (int kk = 0; kk < 2; ++kk) {
                bf16x8 kb = *(const bf16x8*)&Ks[key * 64 + (((kk * 4 + kl) ^ (key & 7)) << 3)];
                a = MFMA16(qa[kk], kb, a);
            }
            s[nb] = a;
        }
        if (kt == qt) {
#pragma unroll
            for (int nb = 0; nb < 4; ++nb) {
                int key = k0 + nb * 16 + lr;
#pragma unroll
                for (int j = 0; j < 4; ++j) {
                    int q = q0 + w * 16 + kl * 4 + j;
                    if (key > q) s[nb][j] = -__builtin_inff();
                }
            }
        }
#pragma unroll
        for (int j = 0; j < 4; ++j) {
            float acc4 = 0.f;
#pragma unroll
            for (int nb = 0; nb < 4; ++nb) {
                float p = __expf(s[nb][j]);
                s[nb][j] = p;
                acc4 += p;
            }
            lsum[j] += acc4;
        }
#pragma unroll
        for (int nb = 0; nb < 4; ++nb)
#pragma unroll
            for (int j = 0; j < 4; ++j)
                Ps[w][(kl * 4 + j) * 72 + nb * 16 + lr] = f2bf(s[nb][j]);
        bf16x8 pa[2];
#pragma unroll
        for (int kk = 0; kk < 2; ++kk)
            pa[kk] = *(const bf16x8*)&Ps[w][lr * 72 + kk * 32 + kl * 8];
#pragma unroll
        for (int db = 0; db < 4; ++db) {
            int d = db * 16 + lr;
#pragma unroll
            for (int kk = 0; kk < 2; ++kk) {
                bf16x8 vb = *(const bf16x8*)&Vs[d * 64 + (((kk * 4 + kl) ^ (d & 7)) << 3)];
                oacc[db] = MFMA16(pa[kk], vb, oacc[db]);
            }
        }
    }
#pragma unroll
    for (int j = 0; j < 4; ++j) {
#pragma unroll
        for (int off = 1; off < 16; off <<= 1) lsum[j] += __shfl_xor(lsum[j], off);
        lsum[j] = 1.f / lsum[j];
    }
#pragma unroll
    for (int db = 0; db < 4; ++db)
#pragma unroll
        for (int j = 0; j < 4; ++j) {
            int q = q0 + w * 16 + kl * 4 + j;
            int col = h * 64 + db * 16 + lr;
            Yg[(size_t)(b * 2048 + q) * 1024 + col] = f2bf(oacc[db][j] * lsum[j]);
        }
}

extern "C" void kernel_launch(void* const* d_in, const int* in_sizes, int n_in,
                              void* d_out, int out_size, void* d_ws, size_t ws_size,
                              hipStream_t stream) {
    const float* x     = (const float*)d_in[0];
    const float* Wqkv  = (const float*)d_in[1];
    const float* bqkv  = (const float*)d_in[2];
    const float* Wproj = (const float*)d_in[3];
    const float* bproj = (const float*)d_in[4];
    float* out = (float*)d_out;

    char* ws = (char*)d_ws;
    u16* xb     = (u16*)(ws);                 // 8,388,608 B  (reused as Vt later)
    u16* WqkvT  = (u16*)(ws + 8388608);       // 6,291,456 B
    u16* WprojT = (u16*)(ws + 14680064);      // 2,097,152 B
    u16* qkv    = (u16*)(ws + 16777216);      // 25,165,824 B : [3][2][16][2048][64]
    u16* Vt   = xb;                            // xb free after GEMM1
    u16* Yatt = qkv + 2 * 4194304;             // v-slot free after transpose_v

    k_convert<<<4096, 256, 0, stream>>>(x, xb);                              // x -> bf16
    k_transpose_convert<<<1536, 256, 0, stream>>>(Wqkv, WqkvT, 1024, 3072);  // Wqkv^T bf16
    k_transpose_convert<<<512, 256, 0, stream>>>(Wproj, WprojT, 1024, 1024); // Wproj^T bf16
    k_gemm_qkv<<<192, 512, 0, stream>>>(xb, WqkvT, bqkv, qkv,
                                        4096, 3072, 1024);                   // qkv (8-phase 256^2)
    k_transpose_v<<<2048, 256, 0, stream>>>(qkv + 2 * 4194304, Vt);          // V -> [d][t]
    k_attn<<<1024, 256, 0, stream>>>(qkv, qkv + 4194304, Vt, Yatt);          // attention
    k_gemm_proj<<<512, 256, 0, stream>>>(Yatt, WprojT, bproj, out,
                                         4096, 1024, 1024);                  // projection
}

// Round 14
// 127.227 us; speedup vs baseline: 1.0483x; 1.0162x over previous
//
#include <hip/hip_runtime.h>
#include <hip/hip_bf16.h>
#include <stdint.h>

typedef unsigned short u16;
typedef __attribute__((ext_vector_type(8))) short bf16x8;   // 8 bf16 = 4 VGPR MFMA frag
typedef __attribute__((ext_vector_type(4))) float f32x4;    // MFMA accumulator frag

#define MFMA16(a,b,c) __builtin_amdgcn_mfma_f32_16x16x32_bf16((a),(b),(c),0,0,0)

__device__ __forceinline__ u16 f2bf(float f) {
    union { float f; uint32_t u; } v; v.f = f;
    return (u16)((v.u + 0x7FFFu + ((v.u >> 16) & 1u)) >> 16);   // RNE
}

// ---------------- x: f32 -> bf16 flat (4 elems/thread) ----------------
__global__ void k_convert(const float* __restrict__ in, u16* __restrict__ out) {
    int i = (blockIdx.x * 256 + threadIdx.x) * 4;
    f32x4 v = *(const f32x4*)(in + i);
    uint64_t p = (uint64_t)f2bf(v[0]) | ((uint64_t)f2bf(v[1]) << 16)
               | ((uint64_t)f2bf(v[2]) << 32) | ((uint64_t)f2bf(v[3]) << 48);
    *(uint64_t*)(out + i) = p;
}

// -------- W [R][NC] f32  ->  WT [NC][R] bf16 (wave-coalesced reads) --------
__global__ void k_transpose_convert(const float* __restrict__ W, u16* __restrict__ WT,
                                    int R, int NC) {
    int id = blockIdx.x * 256 + threadIdx.x;
    int n = id % NC, kc = id / NC;
    bf16x8 o;
#pragma unroll
    for (int i = 0; i < 8; ++i)
        o[i] = (short)f2bf(W[(size_t)(kc * 8 + i) * NC + n]);
    *(bf16x8*)(WT + (size_t)n * R + kc * 8) = o;
}

// -------- V [32][2048][64] bf16 -> Vt [32][64][2048] bf16 --------
__global__ void k_transpose_v(const u16* __restrict__ V, u16* __restrict__ Vt) {
    int id = blockIdx.x * 256 + threadIdx.x;
    int d = id & 63, tc = (id >> 6) & 255, bh = id >> 14;
    const u16* src = V + (size_t)bh * 131072 + d;
    u16* dst = Vt + (size_t)bh * 131072 + (size_t)d * 2048 + tc * 8;
    bf16x8 o;
#pragma unroll
    for (int i = 0; i < 8; ++i) o[i] = (short)src[(size_t)(tc * 8 + i) * 64];
    *(bf16x8*)dst = o;
}

// ---------------- bf16 MFMA GEMM body (r10-verified structure) ----------------
// BM=128, BN=32*NREP, BK=32. 4 waves (2x2), wave tile 64 x 16*NREP.
// 3-deep LDS buffers, counted vmcnt (tile k+2 in flight across barrier).
// XOR chunk swizzle on GLOBAL source + ds_read addr (both-sides, LDS linear).
// MODE 0: scatter to qkv bf16 (q scaled 0.125); MODE 1: fp32 + bias;
// MODE 2: fp32 partial, no bias (split-K).
// Kstride = row stride of A/Bt; Klen = K extent this block reduces.
template<int NREP, int MODE>
__device__ __forceinline__ void gemm_body(
    const u16* __restrict__ A, const u16* __restrict__ Bt,
    const float* __restrict__ bias,
    u16* __restrict__ outQKV, float* __restrict__ outF,
    int M, int N, int tileId, int Kstride, int Klen)
{
    constexpr int BN = 32 * NREP;
    constexpr int WN = 16 * NREP;
    constexpr int BSLOTS = NREP / 2;
    __shared__ __align__(16) u16 As[3][128 * 32];
    __shared__ __align__(16) u16 Bs[3][BN * 32];
    const int tid = threadIdx.x;
    const int nbx = N / BN;
    const int bm = tileId / nbx, bn = tileId % nbx;
    const int m0 = bm << 7, n0 = bn * BN;
    const int l = tid & 63, w = tid >> 6;
    const int wr = w >> 1, wc = w & 1;
    const int kl = l >> 4, lr = l & 15;

    const u16* Ag = A + (size_t)m0 * Kstride;
    const u16* Bg = Bt + (size_t)n0 * Kstride;

    int a_src[2], a_dst[2];
#pragma unroll
    for (int s = 0; s < 2; ++s) {
        int cb = w * 128 + s * 64;
        int c = cb + l;
        int r = c >> 2, kc = c & 3;
        a_src[s] = r * Kstride + ((kc ^ ((r >> 1) & 3)) << 3);
        a_dst[s] = cb << 3;
    }
    int b_src[BSLOTS], b_dst[BSLOTS];
#pragma unroll
    for (int s = 0; s < BSLOTS; ++s) {
        int cb = (w * BSLOTS + s) * 64;
        int c = cb + l;
        int r = c >> 2, kc = c & 3;
        b_src[s] = r * Kstride + ((kc ^ ((r >> 1) & 3)) << 3);
        b_dst[s] = cb << 3;
    }

    int ra[4], rb[NREP];
#pragma unroll
    for (int m = 0; m < 4; ++m) {
        int row = wr * 64 + m * 16 + lr;
        ra[m] = row * 32 + (((kl ^ (row >> 1)) & 3) << 3);
    }
#pragma unroll
    for (int n = 0; n < NREP; ++n) {
        int row = wc * WN + n * 16 + lr;
        rb[n] = row * 32 + (((kl ^ (row >> 1)) & 3) << 3);
    }

    f32x4 acc[4][NREP] = {};

    auto STAGE = [&](int buf, int koff) {
#pragma unroll
        for (int s = 0; s < 2; ++s)
            __builtin_amdgcn_global_load_lds(Ag + a_src[s] + koff,
                                             &As[buf][a_dst[s]], 16, 0, 0);
#pragma unroll
        for (int s = 0; s < BSLOTS; ++s)
            __builtin_amdgcn_global_load_lds(Bg + b_src[s] + koff,
                                             &Bs[buf][b_dst[s]], 16, 0, 0);
    };

    STAGE(0, 0);
    STAGE(1, 32);
    if constexpr (NREP == 4) asm volatile("s_waitcnt vmcnt(4)" ::: "memory");
    else                     asm volatile("s_waitcnt vmcnt(3)" ::: "memory");
    __builtin_amdgcn_s_barrier();
    __builtin_amdgcn_sched_barrier(0);

    const int nK = Klen >> 5;
    int rd = 0;
    for (int ks = 0; ks < nK; ++ks) {
        const bool st = (ks + 2 < nK);
        if (st) {
            int sb = rd + 2; if (sb >= 3) sb -= 3;
            STAGE(sb, (ks + 2) << 5);
        }
        bf16x8 af[4], bfr[NREP];
#pragma unroll
        for (int m = 0; m < 4; ++m) af[m] = *(const bf16x8*)&As[rd][ra[m]];
#pragma unroll
        for (int n = 0; n < NREP; ++n) bfr[n] = *(const bf16x8*)&Bs[rd][rb[n]];
#pragma unroll
        for (int m = 0; m < 4; ++m)
#pragma unroll
            for (int n = 0; n < NREP; ++n)
                acc[m][n] = MFMA16(af[m], bfr[n], acc[m][n]);
        if (ks + 1 < nK) {
            if (st) {
                if constexpr (NREP == 4) asm volatile("s_waitcnt vmcnt(4)" ::: "memory");
                else                     asm volatile("s_waitcnt vmcnt(3)" ::: "memory");
            } else {
                asm volatile("s_waitcnt vmcnt(0)" ::: "memory");
            }
            __builtin_amdgcn_s_barrier();
            __builtin_amdgcn_sched_barrier(0);
        }
        rd = (rd == 2) ? 0 : rd + 1;
    }

    if (MODE == 0) {
#pragma unroll
        for (int n = 0; n < NREP; ++n) {
            int gn = n0 + wc * WN + n * 16 + lr;
            float bv = bias[gn];
            int s = gn >> 10, hd = gn & 1023;
            int hh = hd >> 6, dd = hd & 63;
            float mult = (s == 0) ? 0.125f : 1.0f;   // fold 1/sqrt(64) into q
            size_t base = (size_t)s * 4194304 + (size_t)hh * 131072 + dd;
#pragma unroll
            for (int m = 0; m < 4; ++m)
#pragma unroll
                for (int j = 0; j < 4; ++j) {
                    int gm = m0 + wr * 64 + m * 16 + kl * 4 + j;
                    int bb = gm >> 11, tt = gm & 2047;
                    float val = (acc[m][n][j] + bv) * mult;
                    outQKV[base + (size_t)bb * 2097152 + (size_t)tt * 64] = f2bf(val);
                }
        }
    } else if (MODE == 1) {
#pragma unroll
        for (int n = 0; n < NREP; ++n) {
            int gn = n0 + wc * WN + n * 16 + lr;
            float bv = bias[gn];
#pragma unroll
            for (int m = 0; m < 4; ++m)
#pragma unroll
                for (int j = 0; j < 4; ++j) {
                    int gm = m0 + wr * 64 + m * 16 + kl * 4 + j;
                    outF[(size_t)gm * N + gn] = acc[m][n][j] + bv;
                }
        }
    } else {   // MODE 2: fp32 partial, no bias
#pragma unroll
        for (int n = 0; n < NREP; ++n) {
            int gn = n0 + wc * WN + n * 16 + lr;
#pragma unroll
            for (int m = 0; m < 4; ++m)
#pragma unroll
                for (int j = 0; j < 4; ++j) {
                    int gm = m0 + wr * 64 + m * 16 + kl * 4 + j;
                    outF[(size_t)gm * N + gn] = acc[m][n][j];
                }
        }
    }
}

__global__ __launch_bounds__(256, 3) void k_gemm_qkv(
    const u16* __restrict__ A, const u16* __restrict__ Bt,
    const float* __restrict__ bias, u16* __restrict__ outQKV,
    int M, int N, int K)
{
    gemm_body<4, 0>(A, Bt, bias, outQKV, nullptr, M, N, blockIdx.x, K, K);
}

// fallback: full-K proj, BN=64, grid 512
__global__ __launch_bounds__(256, 3) void k_gemm_proj(
    const u16* __restrict__ A, const u16* __restrict__ Bt,
    const float* __restrict__ bias, float* __restrict__ outF,
    int M, int N, int K)
{
    gemm_body<2, 1>(A, Bt, bias, nullptr, outF, M, N, blockIdx.x, K, K);
}

// split-K=2 proj: 256 tiles (128x128) x 2 K-halves = 512 blocks, fp32 partials
__global__ __launch_bounds__(256, 3) void k_gemm_proj_split(
    const u16* __restrict__ A, const u16* __restrict__ Bt,
    float* __restrict__ partial, int M, int N, int K)
{
    const int nbt = (M >> 7) * (N >> 7);          // 256
    const int split = blockIdx.x / nbt;           // 0 or 1
    const int tile = blockIdx.x % nbt;
    const int kh = K >> 1;                        // 512
    gemm_body<4, 2>(A + split * kh, Bt + split * kh, nullptr, nullptr,
                    partial + (size_t)split * M * N, M, N, tile, K, kh);
}

// out = p0 + p1 + bias  (4 f32/thread, HBM-bound)
__global__ void k_reduce_bias(const float* __restrict__ p,
                              const float* __restrict__ bias,
                              float* __restrict__ out, int total, int N)
{
    int i = (blockIdx.x * 256 + threadIdx.x) * 4;
    f32x4 a = *(const f32x4*)(p + i);
    f32x4 b = *(const f32x4*)(p + total + i);
    f32x4 c = *(const f32x4*)(bias + (i & (N - 1)));
    f32x4 r;
#pragma unroll
    for (int j = 0; j < 4; ++j) r[j] = a[j] + b[j] + c[j];
    *(f32x4*)(out + i) = r;
}

// ---------------- causal flash attention (unchanged) ----------------
__global__ __launch_bounds__(256, 4) void k_attn(
    const u16* __restrict__ Qg, const u16* __restrict__ Kg,
    const u16* __restrict__ Vtg, u16* __restrict__ Yg)
{
    const int bid = blockIdx.x;
    const int bh = bid & 31;
    const int qt = 31 - (bid >> 5);
    const int b = bh >> 4, h = bh & 15;
    const int q0 = qt << 6;
    const int tid = threadIdx.x, l = tid & 63, w = tid >> 6;
    const int kl = l >> 4, lr = l & 15;

    __shared__ __align__(16) u16 Qs[64 * 64];
    __shared__ __align__(16) u16 Ks[64 * 64];
    __shared__ __align__(16) u16 Vs[64 * 64];
    __shared__ __align__(16) u16 Ps[4][16 * 72];

    const u16* Qb = Qg + (size_t)bh * 131072;
    const u16* Kb = Kg + (size_t)bh * 131072;
    const u16* Vb = Vtg + (size_t)bh * 131072;

    const int rr = tid >> 3, ch = tid & 7;
    {
        bf16x8 a = *(const bf16x8*)(Qb + (size_t)(q0 + rr) * 64 + ch * 8);
        bf16x8 c = *(const bf16x8*)(Qb + (size_t)(q0 + rr + 32) * 64 + ch * 8);
        *(bf16x8*)&Qs[rr * 64 + ((ch ^ (rr & 7)) << 3)] = a;
        *(bf16x8*)&Qs[(rr + 32) * 64 + ((ch ^ (rr & 7)) << 3)] = c;
    }
    __syncthreads();
    bf16x8 qa[2];
#pragma unroll
    for (int kk = 0; kk < 2; ++kk) {
        int row = w * 16 + lr;
        qa[kk] = *(const bf16x8*)&Qs[row * 64 + (((kk * 4 + kl) ^ (row & 7)) << 3)];
    }

    f32x4 oacc[4] = {};
    float lsum[4] = {0.f, 0.f, 0.f, 0.f};

    bf16x8 kv0 = *(const bf16x8*)(Kb + (size_t)rr * 64 + ch * 8);
    bf16x8 kv1 = *(const bf16x8*)(Kb + (size_t)(rr + 32) * 64 + ch * 8);
    bf16x8 vv0 = *(const bf16x8*)(Vb + (size_t)rr * 2048 + ch * 8);
    bf16x8 vv1 = *(const bf16x8*)(Vb + (size_t)(rr + 32) * 2048 + ch * 8);

    for (int kt = 0; kt <= qt; ++kt) {
        const int k0 = kt << 6;
        __syncthreads();
        *(bf16x8*)&Ks[rr * 64 + ((ch ^ (rr & 7)) << 3)] = kv0;
        *(bf16x8*)&Ks[(rr + 32) * 64 + ((ch ^ (rr & 7)) << 3)] = kv1;
        *(bf16x8*)&Vs[rr * 64 + ((ch ^ (rr & 7)) << 3)] = vv0;
        *(bf16x8*)&Vs[(rr + 32) * 64 + ((ch ^ (rr & 7)) << 3)] = vv1;
        __syncthreads();
        if (kt < qt) {
            const int k0n = k0 + 64;
            kv0 = *(const bf16x8*)(Kb + (size_t)(k0n + rr) * 64 + ch * 8);
            kv1 = *(const bf16x8*)(Kb + (size_t)(k0n + rr + 32) * 64 + ch * 8);
            vv0 = *(const bf16x8*)(Vb + (size_t)rr * 2048 + k0n + ch * 8);
            vv1 = *(const bf16x8*)(Vb + (size_t)(rr + 32) * 2048 + k0n + ch * 8);
        }

        f32x4 s[4];
#pragma unroll
        for (int nb = 0; nb < 4; ++nb) {
            f32x4 a = {};
            int key = nb * 16 + lr;
#pragma unroll
            for (int kk = 0; kk < 2; ++kk) {
                bf16x8 kb = *(const bf16x8*)&Ks[key * 64 + (((kk * 4 + kl) ^ (key & 7)) << 3)];
                a = MFMA16(qa[kk], kb, a);
            }
            s[nb] = a;
        }
        if (kt == qt) {
#pragma unroll
            for (int nb = 0; nb < 4; ++nb) {
                int key = k0 + nb * 16 + lr;
#pragma unroll
                for (int j = 0; j < 4; ++j) {
                    int q = q0 + w * 16 + kl * 4 + j;
                    if (key > q) s[nb][j] = -__builtin_inff();
                }
            }
        }
#pragma unroll
        for (int j = 0; j < 4; ++j) {
            float acc4 = 0.f;
#pragma unroll
            for (int nb = 0; nb < 4; ++nb) {
                float p = __expf(s[nb][j]);
                s[nb][j] = p;
                acc4 += p;
            }
            lsum[j] += acc4;
        }
#pragma unroll
        for (int nb = 0; nb < 4; ++nb)
#pragma unroll
            for (int j = 0; j < 4; ++j)
                Ps[w][(kl * 4 + j) * 72 + nb * 16 + lr] = f2bf(s[nb][j]);
        bf16x8 pa[2];
#pragma unroll
        for (int kk = 0; kk < 2; ++kk)
            pa[kk] = *(const bf16x8*)&Ps[w][lr * 72 + kk * 32 + kl * 8];
#pragma unroll
        for (int db = 0; db < 4; ++db) {
            int d = db * 16 + lr;
#pragma unroll
            for (int kk = 0; kk < 2; ++kk) {
                bf16x8 vb = *(const bf16x8*)&Vs[d * 64 + (((kk * 4 + kl) ^ (d & 7)) << 3)];
                oacc[db] = MFMA16(pa[kk], vb, oacc[db]);
            }
        }
    }
#pragma unroll
    for (int j = 0; j < 4; ++j) {
#pragma unroll
        for (int off = 1; off < 16; off <<= 1) lsum[j] += __shfl_xor(lsum[j], off);
        lsum[j] = 1.f / lsum[j];
    }
#pragma unroll
    for (int db = 0; db < 4; ++db)
#pragma unroll
        for (int j = 0; j < 4; ++j) {
            int q = q0 + w * 16 + kl * 4 + j;
            int col = h * 64 + db * 16 + lr;
            Yg[(size_t)(b * 2048 + q) * 1024 + col] = f2bf(oacc[db][j] * lsum[j]);
        }
}

extern "C" void kernel_launch(void* const* d_in, const int* in_sizes, int n_in,
                              void* d_out, int out_size, void* d_ws, size_t ws_size,
                              hipStream_t stream) {
    const float* x     = (const float*)d_in[0];
    const float* Wqkv  = (const float*)d_in[1];
    const float* bqkv  = (const float*)d_in[2];
    const float* Wproj = (const float*)d_in[3];
    const float* bproj = (const float*)d_in[4];
    float* out = (float*)d_out;

    char* ws = (char*)d_ws;
    u16* xb     = (u16*)(ws);                 // 8,388,608 B  (reused as Vt later)
    u16* WqkvT  = (u16*)(ws + 8388608);       // 6,291,456 B
    u16* WprojT = (u16*)(ws + 14680064);      // 2,097,152 B
    u16* qkv    = (u16*)(ws + 16777216);      // 25,165,824 B : [3][2][16][2048][64]
    u16* Vt   = xb;                            // xb free after GEMM1
    u16* Yatt = qkv + 2 * 4194304;             // v-slot free after transpose_v

    k_convert<<<4096, 256, 0, stream>>>(x, xb);                              // x -> bf16
    k_transpose_convert<<<1536, 256, 0, stream>>>(Wqkv, WqkvT, 1024, 3072);  // Wqkv^T bf16
    k_transpose_convert<<<512, 256, 0, stream>>>(Wproj, WprojT, 1024, 1024); // Wproj^T bf16
    k_gemm_qkv<<<768, 256, 0, stream>>>(xb, WqkvT, bqkv, qkv,
                                        4096, 3072, 1024);                   // qkv (r10 128^2)
    k_transpose_v<<<2048, 256, 0, stream>>>(qkv + 2 * 4194304, Vt);          // V -> [d][t]
    k_attn<<<1024, 256, 0, stream>>>(qkv, qkv + 4194304, Vt, Yatt);          // attention

    const size_t pbase = 41943040;             // end of current ws usage (40 MB)
    const size_t need  = pbase + 2u * 16777216; // + two fp32 4096x1024 partials
    if (ws_size >= need) {
        float* partial = (float*)(ws + pbase);
        k_gemm_proj_split<<<512, 256, 0, stream>>>(Yatt, WprojT, partial,
                                                   4096, 1024, 1024);        // split-K=2
        k_reduce_bias<<<4096, 256, 0, stream>>>(partial, bproj, out,
                                                4194304, 1024);              // p0+p1+bias
    } else {
        k_gemm_proj<<<512, 256, 0, stream>>>(Yatt, WprojT, bproj, out,
                                             4096, 1024, 1024);              // fallback
    }
}